// Round 4
// baseline (32.396 us; speedup 1.0000x reference)
//
#include <hip/hip_runtime.h>
#include <hip/hip_bf16.h>
#include <math.h>

#define BB 2

__device__ __forceinline__ float eluf(float v) {
  return v > 0.f ? v : __expf(v) - 1.f;
}

__device__ __forceinline__ float dot4(float4 a, float4 b) {
  return a.x * b.x + a.y * b.y + a.z * b.z + a.w * b.w;
}

__device__ __forceinline__ float b2f(unsigned short u) {
  union { unsigned int i; float f; } v;
  v.i = ((unsigned int)u) << 16;
  return v.f;
}

// prep kernel:
//  blocks 0..31   : wredT[sel][K][h] = colsum - rowsum of wm_di / wm_dd (separable DI/DD)
//  blocks 32..543 : wmA[h][e] = bf16( 0.0625*(wm_ndi[h,I,J] - wm_ndi[h,J,I]) ) on the
//                   antisymmetric rectangle mapping e -> (I = e>>5, J = (I+1+(e&31))&63),
//                   zeroed on the 32 duplicate d=32 columns (e&31==31 && I>=32).
__global__ void prep_kernel(const float* __restrict__ wm_di,
                            const float* __restrict__ wm_ndi,
                            const float* __restrict__ wm_dd,
                            float* __restrict__ ws) {
  float* wredT = ws;  // 2*4096 floats
  __hip_bfloat16* wmA = (__hip_bfloat16*)(ws + 8192);  // 64*2048 bf16
  if (blockIdx.x < 32) {
    int t = blockIdx.x * 256 + threadIdx.x;  // 0..8191
    int sel = t >> 12, idx = t & 4095;
    int h = idx >> 6, K = idx & 63;
    const float* w = (sel ? wm_dd : wm_di) + h * 4096;
    float cs = 0.f, rs = 0.f;
#pragma unroll 8
    for (int I = 0; I < 64; ++I) cs += w[I * 64 + K];
#pragma unroll 8
    for (int J = 0; J < 64; ++J) rs += w[K * 64 + J];
    wredT[sel * 4096 + K * 64 + h] = cs - rs;
  } else {
    int gid = (blockIdx.x - 32) * 256 + threadIdx.x;  // 0..131071
    int h = gid >> 11, e = gid & 2047;
    int I = e >> 5, tt = e & 31;
    int J = (I + 1 + tt) & 63;
    float v = 0.f;
    if (!(tt == 31 && I >= 32)) {
      const float* w = wm_ndi + h * 4096;
      v = 0.0625f * (w[I * 64 + J] - w[J * 64 + I]);
    }
    wmA[h * 2048 + e] = __float2bfloat16(v);
  }
}

__global__ __launch_bounds__(512) void fused_kernel(
    const float* __restrict__ x,
    const float* __restrict__ b_di, const float* __restrict__ b_ndi,
    const float* __restrict__ b_dd,
    const float* __restrict__ fcw_di, const float* __restrict__ fcb_di,
    const float* __restrict__ fcw_ndi, const float* __restrict__ fcb_ndi,
    const float* __restrict__ fcw_dd, const float* __restrict__ fcb_dd,
    const float* __restrict__ fc1_w, const float* __restrict__ fc1_b,
    const float* __restrict__ fc2_w, const float* __restrict__ fc2_b,
    const float* __restrict__ ws,
    float* __restrict__ out) {
  const float* __restrict__ wredT = ws;                                   // [2][64][64]
  const unsigned short* __restrict__ wmA = (const unsigned short*)(ws + 8192);  // [64][2048] bf16

  __shared__ float xs[BB][256];
  __shared__ float pxs[BB][64];
  __shared__ float pds[BB][64];
  __shared__ float pnA[BB][2048];   // antisym rectangle of pooled NDI
  __shared__ float hh[3][BB][64];
  __shared__ float emb[BB][144];
  __shared__ float f1v[BB][48];

  const int t = threadIdx.x;
  const int b0 = blockIdx.x * BB;

  // ---- load x rows: 512 threads = 2 rows x 256 cols ----
  {
    const int r = t >> 8, c = t & 255;
    xs[r][c] = x[(b0 + r) * 256 + c];
  }
  __syncthreads();

  // ---- pooled x and pooled (telescoped) diff: t<128 ----
  if (t < BB * 64) {
    const int r = t >> 6, m = t & 63;
    const float* __restrict__ xr = xs[r];
    const int b4 = 4 * m;
    pxs[r][m] = 0.25f * (xr[b4] + xr[b4 + 1] + xr[b4 + 2] + xr[b4 + 3]);
    const int i3 = min(b4 + 4, 255), i4 = min(b4 + 5, 255);
    const float smv = 0.2f * (xr[b4 + 1] + xr[b4 + 2] + xr[b4 + 3] + xr[i3] + xr[i4]);
    float prev = __shfl_up(smv, 1, 64);
    if (m == 0) prev = xr[0];
    pds[r][m] = 0.25f * (smv - prev);
  }

  // ---- pooled NDI, antisymmetric half only: 8 entries/thread ----
  for (int cc = t; cc < BB * 2048; cc += 512) {
    const int r = cc >> 11;
    const int e = cc & 2047;
    const int I = e >> 5;
    const int J = (I + 1 + (e & 31)) & 63;
    const float4 xiv = *(const float4*)&xs[r][I << 2];
    const float4 xjv = *(const float4*)&xs[r][J << 2];
    const float xi_a[4] = {xiv.x, xiv.y, xiv.z, xiv.w};
    const float xj_a[4] = {xjv.x + 1e-5f, xjv.y + 1e-5f, xjv.z + 1e-5f, xjv.w + 1e-5f};
    const float xn_a[4] = {xjv.x, xjv.y, xjv.z, xjv.w};
    float s = 0.f;
#pragma unroll
    for (int a = 0; a < 4; ++a) {
#pragma unroll
      for (int c = 0; c < 4; ++c) {
        const float num = xn_a[c] - xi_a[a];
        const float den = xj_a[c] + xi_a[a];
        s += num * __builtin_amdgcn_rcpf(den);
      }
    }
    pnA[r][e] = s;  // 1/16 folded into wmA
  }
  __syncthreads();

  // ---- NDI einsum over antisym half: 8 waves x 8 heads x 2 rows, 8 k-iters ----
  {
    const int wave = t >> 6, lane = t & 63;
    const int h0 = wave * 8;
    const ushort4* __restrict__ w0 = (const ushort4*)(wmA + (h0 + 0) * 2048);
    const ushort4* __restrict__ w1 = (const ushort4*)(wmA + (h0 + 1) * 2048);
    const ushort4* __restrict__ w2 = (const ushort4*)(wmA + (h0 + 2) * 2048);
    const ushort4* __restrict__ w3 = (const ushort4*)(wmA + (h0 + 3) * 2048);
    const ushort4* __restrict__ w4 = (const ushort4*)(wmA + (h0 + 4) * 2048);
    const ushort4* __restrict__ w5 = (const ushort4*)(wmA + (h0 + 5) * 2048);
    const ushort4* __restrict__ w6 = (const ushort4*)(wmA + (h0 + 6) * 2048);
    const ushort4* __restrict__ w7 = (const ushort4*)(wmA + (h0 + 7) * 2048);
    float acc[16];  // q = r*8 + g
#pragma unroll
    for (int q = 0; q < 16; ++q) acc[q] = 0.f;
#pragma unroll 2
    for (int k = 0; k < 8; ++k) {
      const int e4 = k * 64 + lane;
      const ushort4 u0 = w0[e4], u1 = w1[e4], u2 = w2[e4], u3 = w3[e4];
      const ushort4 u4 = w4[e4], u5 = w5[e4], u6 = w6[e4], u7 = w7[e4];
      const float4 p0 = *(const float4*)&pnA[0][e4 << 2];
      const float4 p1 = *(const float4*)&pnA[1][e4 << 2];
      float4 wv;
      wv = make_float4(b2f(u0.x), b2f(u0.y), b2f(u0.z), b2f(u0.w));
      acc[0] += dot4(wv, p0); acc[8]  += dot4(wv, p1);
      wv = make_float4(b2f(u1.x), b2f(u1.y), b2f(u1.z), b2f(u1.w));
      acc[1] += dot4(wv, p0); acc[9]  += dot4(wv, p1);
      wv = make_float4(b2f(u2.x), b2f(u2.y), b2f(u2.z), b2f(u2.w));
      acc[2] += dot4(wv, p0); acc[10] += dot4(wv, p1);
      wv = make_float4(b2f(u3.x), b2f(u3.y), b2f(u3.z), b2f(u3.w));
      acc[3] += dot4(wv, p0); acc[11] += dot4(wv, p1);
      wv = make_float4(b2f(u4.x), b2f(u4.y), b2f(u4.z), b2f(u4.w));
      acc[4] += dot4(wv, p0); acc[12] += dot4(wv, p1);
      wv = make_float4(b2f(u5.x), b2f(u5.y), b2f(u5.z), b2f(u5.w));
      acc[5] += dot4(wv, p0); acc[13] += dot4(wv, p1);
      wv = make_float4(b2f(u6.x), b2f(u6.y), b2f(u6.z), b2f(u6.w));
      acc[6] += dot4(wv, p0); acc[14] += dot4(wv, p1);
      wv = make_float4(b2f(u7.x), b2f(u7.y), b2f(u7.z), b2f(u7.w));
      acc[7] += dot4(wv, p0); acc[15] += dot4(wv, p1);
    }
    // multi-value butterfly reduce: lane l ends holding full sum of acc[l&15]
    // (q bit i selected by lane bit i).
#pragma unroll
    for (int i = 0; i < 8; ++i) {
      const float u = acc[2 * i], v = acc[2 * i + 1];
      const float sel = (lane & 1) ? u : v;
      const float sh = __shfl_xor(sel, 1, 64);
      acc[i] = ((lane & 1) ? v : u) + sh;
    }
#pragma unroll
    for (int i = 0; i < 4; ++i) {
      const float u = acc[2 * i], v = acc[2 * i + 1];
      const float sel = (lane & 2) ? u : v;
      const float sh = __shfl_xor(sel, 2, 64);
      acc[i] = ((lane & 2) ? v : u) + sh;
    }
#pragma unroll
    for (int i = 0; i < 2; ++i) {
      const float u = acc[2 * i], v = acc[2 * i + 1];
      const float sel = (lane & 4) ? u : v;
      const float sh = __shfl_xor(sel, 4, 64);
      acc[i] = ((lane & 4) ? v : u) + sh;
    }
    {
      const float u = acc[0], v = acc[1];
      const float sel = (lane & 8) ? u : v;
      const float sh = __shfl_xor(sel, 8, 64);
      acc[0] = ((lane & 8) ? v : u) + sh;
    }
    float rsum = acc[0];
    rsum += __shfl_xor(rsum, 16, 64);
    rsum += __shfl_xor(rsum, 32, 64);
    if (lane < 16) {
      const int rr = lane >> 3, g = lane & 7;
      hh[1][rr][h0 + g] = eluf(rsum + b_ndi[h0 + g]);
    }
  }

  // ---- DI / DD head projections via reduced weights (same barrier interval) ----
  if (t < BB * 64) {
    const int r = t >> 6, h = t & 63;
    float adi = b_di[h], add_ = b_dd[h];
#pragma unroll 8
    for (int K = 0; K < 64; ++K) {
      adi  += pxs[r][K] * wredT[K * 64 + h];
      add_ += pds[r][K] * wredT[4096 + K * 64 + h];
    }
    hh[0][r][h] = eluf(adi);
    hh[2][r][h] = eluf(add_);
  }
  __syncthreads();

  // ---- per-picker fc: HEAD(64) -> EMB(48) ----
  if (t < BB * 144) {
    const int r = t / 144;
    const int k = t - r * 144;
    const int pick = k / 48;
    const int e = k - pick * 48;
    const float* __restrict__ fw = (pick == 0) ? fcw_di : (pick == 1) ? fcw_ndi : fcw_dd;
    const float* __restrict__ fb = (pick == 0) ? fcb_di : (pick == 1) ? fcb_ndi : fcb_dd;
    float a = fb[e];
#pragma unroll 8
    for (int hq = 0; hq < 64; ++hq) a += hh[pick][r][hq] * fw[e * 64 + hq];
    emb[r][k] = eluf(a);
  }
  __syncthreads();

  // ---- fc1: 144 -> 48, elu ----
  if (t < BB * 48) {
    const int r = t / 48, o = t - (t / 48) * 48;
    float a = fc1_b[o];
#pragma unroll 8
    for (int k = 0; k < 144; ++k) a += emb[r][k] * fc1_w[o * 144 + k];
    f1v[r][o] = eluf(a);
  }
  __syncthreads();

  // ---- fc2: 48 -> 20 ----
  if (t < BB * 20) {
    const int r = t / 20, o = t - (t / 20) * 20;
    float a = fc2_b[o];
#pragma unroll
    for (int j = 0; j < 48; ++j) a += f1v[r][j] * fc2_w[o * 48 + j];
    out[(b0 + r) * 20 + o] = a;
  }
}

extern "C" void kernel_launch(void* const* d_in, const int* in_sizes, int n_in,
                              void* d_out, int out_size, void* d_ws, size_t ws_size,
                              hipStream_t stream) {
  const float* x       = (const float*)d_in[0];
  const float* wm_di   = (const float*)d_in[1];
  const float* b_di    = (const float*)d_in[2];
  const float* fcw_di  = (const float*)d_in[3];
  const float* fcb_di  = (const float*)d_in[4];
  const float* wm_ndi  = (const float*)d_in[5];
  const float* b_ndi   = (const float*)d_in[6];
  const float* fcw_ndi = (const float*)d_in[7];
  const float* fcb_ndi = (const float*)d_in[8];
  const float* wm_dd   = (const float*)d_in[9];
  const float* b_dd    = (const float*)d_in[10];
  const float* fcw_dd  = (const float*)d_in[11];
  const float* fcb_dd  = (const float*)d_in[12];
  const float* fc1_w   = (const float*)d_in[13];
  const float* fc1_b   = (const float*)d_in[14];
  const float* fc2_w   = (const float*)d_in[15];
  const float* fc2_b   = (const float*)d_in[16];
  float* out = (float*)d_out;
  float* ws  = (float*)d_ws;  // wredT: 8192 f32 (32 KB) + wmA: 131072 bf16 (256 KB)

  prep_kernel<<<544, 256, 0, stream>>>(wm_di, wm_ndi, wm_dd, ws);
  fused_kernel<<<512, 512, 0, stream>>>(
      x, b_di, b_ndi, b_dd,
      fcw_di, fcb_di, fcw_ndi, fcb_ndi, fcw_dd, fcb_dd,
      fc1_w, fc1_b, fc2_w, fc2_b, ws, out);
}